// Round 1
// baseline (15155.417 us; speedup 1.0000x reference)
//
#include <hip/hip_runtime.h>
#include <hip/hip_bf16.h>

// ---- problem constants ----
#define L_SEQ  2048
#define HID_   4096
#define H_     128
#define P_     64
#define N_     128
#define G_     8
#define CS_    256
#define NC_    8
#define INTER_ 8192
#define CONV_  10240
#define PROJ_  18560

typedef __attribute__((ext_vector_type(4))) float f32x4;
typedef __attribute__((ext_vector_type(8))) short short8;

__device__ __forceinline__ short f2bf(float f) {
  unsigned u = __builtin_bit_cast(unsigned, f);
  u += 0x7fffu + ((u >> 16) & 1u);          // RNE truncation to bf16
  return (short)(u >> 16);
}
__device__ __forceinline__ float sigm(float x) { return 1.0f / (1.0f + __expf(-x)); }

// ================= GEMM: C[m][n] = sum_k A[m][k] * B[n][k] =================
// 128x128 tile, 4 waves (2x2), BK=32, reg-staged f32->bf16 into LDS.
template<int ABF16>
__global__ __launch_bounds__(256)
void gemm_bt(const void* __restrict__ Ap, const float* __restrict__ Bp,
             float* __restrict__ C, int M, int N, int K)
{
  __shared__ short As[128 * 32];
  __shared__ short Bs[128 * 32];
  const int tid  = threadIdx.x;
  const int lane = tid & 63;
  const int wave = tid >> 6;
  const int wr = wave >> 1, wc = wave & 1;
  const int m0 = blockIdx.y << 7;
  const int n0 = blockIdx.x << 7;
  const int fr = lane & 15;          // fragment row/col within 16
  const int kb = lane >> 4;          // k-block 0..3 (8 k each)

  f32x4 acc[4][4];
  #pragma unroll
  for (int a = 0; a < 4; ++a)
    #pragma unroll
    for (int b = 0; b < 4; ++b) acc[a][b] = f32x4{0.f, 0.f, 0.f, 0.f};

  const int srow = tid >> 1;          // 128 rows, 2 threads per row
  const int scol = (tid & 1) << 4;    // 16 elements each
  short* adst = &As[srow * 32 + scol];
  short* bdst = &Bs[srow * 32 + scol];

  for (int k0 = 0; k0 < K; k0 += 32) {
    if (ABF16) {
      const short* asrc = (const short*)Ap + (long)(m0 + srow) * K + k0 + scol;
      *(short8*)adst       = *(const short8*)asrc;
      *(short8*)(adst + 8) = *(const short8*)(asrc + 8);
    } else {
      const float* asrc = (const float*)Ap + (long)(m0 + srow) * K + k0 + scol;
      #pragma unroll
      for (int q = 0; q < 16; q += 4) {
        f32x4 v = *(const f32x4*)(asrc + q);
        adst[q + 0] = f2bf(v.x); adst[q + 1] = f2bf(v.y);
        adst[q + 2] = f2bf(v.z); adst[q + 3] = f2bf(v.w);
      }
    }
    {
      const float* bsrc = Bp + (long)(n0 + srow) * K + k0 + scol;
      #pragma unroll
      for (int q = 0; q < 16; q += 4) {
        f32x4 v = *(const f32x4*)(bsrc + q);
        bdst[q + 0] = f2bf(v.x); bdst[q + 1] = f2bf(v.y);
        bdst[q + 2] = f2bf(v.z); bdst[q + 3] = f2bf(v.w);
      }
    }
    __syncthreads();
    short8 af[4], bfv[4];
    #pragma unroll
    for (int mi = 0; mi < 4; ++mi)
      af[mi] = *(const short8*)&As[(wr * 64 + mi * 16 + fr) * 32 + kb * 8];
    #pragma unroll
    for (int ni = 0; ni < 4; ++ni)
      bfv[ni] = *(const short8*)&Bs[(wc * 64 + ni * 16 + fr) * 32 + kb * 8];
    #pragma unroll
    for (int mi = 0; mi < 4; ++mi)
      #pragma unroll
      for (int ni = 0; ni < 4; ++ni)
        acc[mi][ni] = __builtin_amdgcn_mfma_f32_16x16x32_bf16(af[mi], bfv[ni], acc[mi][ni], 0, 0, 0);
    __syncthreads();
  }
  // C/D layout: col = lane&15, row = (lane>>4)*4 + r   [guide m89/m91]
  const int r0 = (lane >> 4) << 2;
  #pragma unroll
  for (int mi = 0; mi < 4; ++mi)
    #pragma unroll
    for (int ni = 0; ni < 4; ++ni) {
      float* cp = C + (long)(m0 + wr * 64 + mi * 16 + r0) * N + n0 + wc * 64 + ni * 16 + fr;
      #pragma unroll
      for (int r = 0; r < 4; ++r) cp[(long)r * N] = acc[mi][ni][r];
    }
}

// ================= conv1d (depthwise K=4, causal) + bias + silu =================
__global__ __launch_bounds__(256)
void conv_silu(const float* __restrict__ proj, const float* __restrict__ cw,
               const float* __restrict__ cb, float* __restrict__ xbc)
{
  const int idx = blockIdx.x * 256 + threadIdx.x;   // 2048 * 2560
  const int c4  = idx % 2560;
  const int l   = idx / 2560;
  const int ch  = c4 << 2;
  f32x4 w0 = *(const f32x4*)&cw[(ch + 0) * 4];
  f32x4 w1 = *(const f32x4*)&cw[(ch + 1) * 4];
  f32x4 w2 = *(const f32x4*)&cw[(ch + 2) * 4];
  f32x4 w3 = *(const f32x4*)&cw[(ch + 3) * 4];
  f32x4 a  = *(const f32x4*)&cb[ch];
  #pragma unroll
  for (int t = 0; t < 4; ++t) {
    const int ls = l - 3 + t;
    if (ls >= 0) {
      f32x4 xv = *(const f32x4*)&proj[(long)ls * PROJ_ + INTER_ + ch];
      a.x += xv.x * w0[t];
      a.y += xv.y * w1[t];
      a.z += xv.z * w2[t];
      a.w += xv.w * w3[t];
    }
  }
  a.x = a.x * sigm(a.x);  a.y = a.y * sigm(a.y);
  a.z = a.z * sigm(a.z);  a.w = a.w * sigm(a.w);
  *(f32x4*)&xbc[(long)l * CONV_ + ch] = a;
}

// ================= dt softplus + per-chunk cumsum (wave scan) =================
__global__ void dtcum(const float* __restrict__ proj, const float* __restrict__ dt_bias,
                      const float* __restrict__ A_log, float* __restrict__ dtv,
                      float* __restrict__ cumv, float* __restrict__ dlw,
                      float* __restrict__ cdec)
{
  const int c = blockIdx.x, h = blockIdx.y, lane = threadIdx.x;  // 64 threads
  const float A    = -__expf(A_log[h]);
  const float bias = dt_bias[h];
  float d[4], cl[4];
  float run = 0.f;
  #pragma unroll
  for (int q = 0; q < 4; ++q) {
    const int i = lane * 4 + q;
    float z  = proj[(long)((c << 8) + i) * PROJ_ + INTER_ + CONV_ + h] + bias;
    float dt = (z > 20.f) ? z : log1pf(__expf(z));
    d[q] = dt;
    run += dt * A;
    cl[q] = run;
  }
  float s = run;
  #pragma unroll
  for (int off = 1; off < 64; off <<= 1) {
    float o = __shfl_up(s, off);
    if (lane >= off) s += o;
  }
  const float excl  = s - run;
  const float total = __shfl(s, 63);
  const long  sb    = ((long)(c * 128 + h)) << 8;
  #pragma unroll
  for (int q = 0; q < 4; ++q) {
    const int   i   = lane * 4 + q;
    const float cum = excl + cl[q];
    dtv[sb + i]  = d[q];
    cumv[sb + i] = cum;
    dlw[sb + i]  = d[q] * __expf(total - cum);   // dt_j * exp(cum_last - cum_j)
  }
  if (lane == 0) cdec[c * 128 + h] = __expf(total);
}

// ================= intra-chunk: scores -> y_intra, plus chunk states =================
// block = (chunk c, head h), 256 threads. Lane owns one i (interleaved across waves
// for causal-work balance). j processed in tiles of 16 via LDS.
#define JJT 16
__global__ __launch_bounds__(256)
void ssd_intra(const float* __restrict__ xbc, const float* __restrict__ dtv,
               const float* __restrict__ cumv, const float* __restrict__ dlw,
               float* __restrict__ y, float* __restrict__ states)
{
  __shared__ float Bt[JJT * 128];
  __shared__ float xt[JJT * 64];
  __shared__ float wjs[JJT], cjs[JJT], dls[JJT];
  const int c = blockIdx.x, h = blockIdx.y, g = h >> 4;
  const int tid = threadIdx.x, lane = tid & 63, wave = tid >> 6;
  const int i   = ((lane >> 3) << 5) + (wave << 3) + (lane & 7);  // bijective 0..255
  const int l_i = (c << 8) + i;
  const long sb = ((long)(c * 128 + h)) << 8;
  const float cum_i = cumv[sb + i];
  const f32x4* Cg = (const f32x4*)(xbc + (long)l_i * CONV_ + INTER_ + 1024 + g * 128);

  f32x4 yv[16];
  #pragma unroll
  for (int q = 0; q < 16; ++q) yv[q] = f32x4{0.f, 0.f, 0.f, 0.f};
  f32x4 st[8];
  #pragma unroll
  for (int q = 0; q < 8; ++q) st[q] = f32x4{0.f, 0.f, 0.f, 0.f};
  const int sn  = tid & 127;            // state n index
  const int sp0 = (tid >> 7) << 5;      // state p base (0 or 32)

  const int trow = tid >> 4;            // 16 rows
  const int tc8  = (tid & 15) << 3;     // B cols, 8 each
  const int tc4  = (tid & 15) << 2;     // x cols, 4 each

  for (int jt = 0; jt < 16; ++jt) {
    const int j0 = jt << 4;
    {
      const float* bsrc = xbc + (long)((c << 8) + j0 + trow) * CONV_ + INTER_ + g * 128 + tc8;
      *(f32x4*)&Bt[trow * 128 + tc8]     = *(const f32x4*)(bsrc);
      *(f32x4*)&Bt[trow * 128 + tc8 + 4] = *(const f32x4*)(bsrc + 4);
      const float* xsrc = xbc + (long)((c << 8) + j0 + trow) * CONV_ + h * 64 + tc4;
      *(f32x4*)&xt[trow * 64 + tc4] = *(const f32x4*)(xsrc);
      if (tid < JJT) {
        wjs[tid] = dtv[sb + j0 + tid];
        cjs[tid] = cumv[sb + j0 + tid];
        dls[tid] = dlw[sb + j0 + tid];
      }
    }
    __syncthreads();
    // ---- states: st[p][n] += dlw_j * B[j][n] * x[j][p] ----
    #pragma unroll
    for (int jj = 0; jj < JJT; ++jj) {
      const float wb = dls[jj] * Bt[jj * 128 + sn];
      const f32x4* xr = (const f32x4*)&xt[jj * 64 + sp0];
      #pragma unroll
      for (int pp = 0; pp < 8; ++pp) st[pp] += wb * xr[pp];
    }
    // ---- scores: s_j = C_i . B_j ----
    float sj[JJT];
    #pragma unroll
    for (int jj = 0; jj < JJT; ++jj) sj[jj] = 0.f;
    for (int n4 = 0; n4 < 32; ++n4) {
      const f32x4 cv = Cg[n4];
      #pragma unroll
      for (int jj = 0; jj < JJT; ++jj) {
        const f32x4 bv = *(const f32x4*)&Bt[jj * 128 + (n4 << 2)];
        sj[jj] += cv.x * bv.x + cv.y * bv.y + cv.z * bv.z + cv.w * bv.w;
      }
    }
    // ---- decay+mask, y += s * x_j ----
    #pragma unroll
    for (int jj = 0; jj < JJT; ++jj) {
      const float e  = __expf(cum_i - cjs[jj]) * wjs[jj];
      const float sc = (i >= j0 + jj) ? sj[jj] * e : 0.0f;
      const f32x4* xr = (const f32x4*)&xt[jj * 64];
      #pragma unroll
      for (int p4 = 0; p4 < 16; ++p4) yv[p4] += sc * xr[p4];
    }
    __syncthreads();
  }
  float* yo = y + (long)l_i * INTER_ + h * 64;
  #pragma unroll
  for (int p4 = 0; p4 < 16; ++p4) *(f32x4*)&yo[p4 << 2] = yv[p4];
  float* so = states + (((long)c * 128 + h) << 13);
  #pragma unroll
  for (int q = 0; q < 8; ++q)
    #pragma unroll
    for (int e = 0; e < 4; ++e)
      so[(long)(sp0 + q * 4 + e) * 128 + sn] = st[q][e];
}

// ================= sequential chunk-state scan =================
__global__ void ssd_scan(const float* __restrict__ states, const float* __restrict__ cdec,
                         float* __restrict__ prev)
{
  const int idx = blockIdx.x * 256 + threadIdx.x;   // 128*64*128 = 1M
  const int h   = idx >> 13;
  float s = 0.f;
  #pragma unroll
  for (int c = 0; c < 8; ++c) {
    prev[((long)c << 20) + idx] = s;
    s = cdec[c * 128 + h] * s + states[((long)c << 20) + idx];
  }
}

// ================= inter-chunk contribution + D*x =================
__global__ __launch_bounds__(256)
void ssd_inter(const float* __restrict__ xbc, const float* __restrict__ cumv,
               const float* __restrict__ prev, const float* __restrict__ Dp,
               float* __restrict__ y)
{
  __shared__ float pv[8192];   // prev[p][n] 32 KB
  const int c = blockIdx.x, h = blockIdx.y, g = h >> 4;
  const int tid = threadIdx.x;
  const float* ps = prev + (((long)c * 128 + h) << 13);
  #pragma unroll
  for (int q = 0; q < 8; ++q)
    *(f32x4*)&pv[tid * 4 + q * 1024] = *(const f32x4*)&ps[tid * 4 + q * 1024];
  __syncthreads();
  const int i = tid, l_i = (c << 8) + i;
  const float ec = __expf(cumv[(((long)c * 128 + h) << 8) + i]);
  const f32x4* Cg = (const f32x4*)(xbc + (long)l_i * CONV_ + INTER_ + 1024 + g * 128);
  float acc[64];
  #pragma unroll
  for (int p = 0; p < 64; ++p) acc[p] = 0.f;
  const f32x4* pv4 = (const f32x4*)pv;
  for (int n4 = 0; n4 < 32; ++n4) {
    const f32x4 cv = Cg[n4];
    #pragma unroll
    for (int p = 0; p < 64; ++p) {
      const f32x4 b = pv4[p * 32 + n4];
      acc[p] += cv.x * b.x + cv.y * b.y + cv.z * b.z + cv.w * b.w;
    }
  }
  const float Dh = Dp[h];
  float* yo = y + (long)l_i * INTER_ + h * 64;
  const float* xg = xbc + (long)l_i * CONV_ + h * 64;
  #pragma unroll
  for (int p4 = 0; p4 < 16; ++p4) {
    f32x4 yvv = *(const f32x4*)&yo[p4 * 4];
    f32x4 xv  = *(const f32x4*)&xg[p4 * 4];
    f32x4 r;
    r.x = yvv.x + ec * acc[p4 * 4 + 0] + Dh * xv.x;
    r.y = yvv.y + ec * acc[p4 * 4 + 1] + Dh * xv.y;
    r.z = yvv.z + ec * acc[p4 * 4 + 2] + Dh * xv.z;
    r.w = yvv.w + ec * acc[p4 * 4 + 3] + Dh * xv.w;
    *(f32x4*)&yo[p4 * 4] = r;
  }
}

// ================= gate (silu) * y, group-RMS norm, -> bf16 =================
__global__ __launch_bounds__(256)
void gate_norm(const float* __restrict__ y, const float* __restrict__ proj,
               const float* __restrict__ norm_w, short* __restrict__ gout)
{
  const int l = blockIdx.x, tid = threadIdx.x;
  const float* yr = y    + (long)l * INTER_ + tid * 32;
  const float* gr = proj + (long)l * PROJ_  + tid * 32;
  float v[32];
  float ss = 0.f;
  #pragma unroll
  for (int q4 = 0; q4 < 8; ++q4) {
    f32x4 yv = *(const f32x4*)&yr[q4 * 4];
    f32x4 gv = *(const f32x4*)&gr[q4 * 4];
    float a0 = yv.x * (gv.x * sigm(gv.x));
    float a1 = yv.y * (gv.y * sigm(gv.y));
    float a2 = yv.z * (gv.z * sigm(gv.z));
    float a3 = yv.w * (gv.w * sigm(gv.w));
    v[q4 * 4 + 0] = a0; v[q4 * 4 + 1] = a1; v[q4 * 4 + 2] = a2; v[q4 * 4 + 3] = a3;
    ss += a0 * a0 + a1 * a1 + a2 * a2 + a3 * a3;
  }
  // 32 threads per group (1024 cols); reduce within half-wave
  #pragma unroll
  for (int off = 16; off > 0; off >>= 1) ss += __shfl_xor(ss, off);
  const float scale = rsqrtf(ss * (1.0f / 1024.0f) + 1e-5f);
  const float* nw = norm_w + tid * 32;
  short* go = gout + (long)l * INTER_ + tid * 32;
  #pragma unroll
  for (int q = 0; q < 32; q += 8) {
    short8 o;
    #pragma unroll
    for (int e = 0; e < 8; ++e) o[e] = f2bf(v[q + e] * scale * nw[q + e]);
    *(short8*)&go[q] = o;
  }
}

// ================= launcher =================
extern "C" void kernel_launch(void* const* d_in, const int* in_sizes, int n_in,
                              void* d_out, int out_size, void* d_ws, size_t ws_size,
                              hipStream_t stream)
{
  (void)in_sizes; (void)n_in; (void)out_size; (void)ws_size;
  const float* input     = (const float*)d_in[0];
  const float* in_proj_w = (const float*)d_in[1];
  const float* conv_w    = (const float*)d_in[2];
  const float* conv_b    = (const float*)d_in[3];
  const float* dt_bias   = (const float*)d_in[4];
  const float* A_log     = (const float*)d_in[5];
  const float* Dp        = (const float*)d_in[6];
  const float* norm_w    = (const float*)d_in[7];
  const float* out_w     = (const float*)d_in[8];
  float* out = (float*)d_out;

  char* ws = (char*)d_ws;
  float* proj   = (float*)ws;  ws += (size_t)2048 * 18560 * 4;   // 152.0 MB
  float* xbc    = (float*)ws;  ws += (size_t)2048 * 10240 * 4;   //  83.9 MB
  float* y      = (float*)ws;  ws += (size_t)2048 * 8192 * 4;    //  67.1 MB
  float* states = (float*)ws;  ws += (size_t)8 * 1048576 * 4;    //  33.6 MB
  float* prev   = (float*)ws;  ws += (size_t)8 * 1048576 * 4;    //  33.6 MB
  short* g      = (short*)ws;  ws += (size_t)2048 * 8192 * 2;    //  33.6 MB
  float* dtv    = (float*)ws;  ws += (size_t)262144 * 4;
  float* cumv   = (float*)ws;  ws += (size_t)262144 * 4;
  float* dlwv   = (float*)ws;  ws += (size_t)262144 * 4;
  float* cdec   = (float*)ws;  ws += 4096;

  gemm_bt<0><<<dim3(145, 16), 256, 0, stream>>>(input, in_proj_w, proj, 2048, PROJ_, HID_);
  conv_silu<<<20480, 256, 0, stream>>>(proj, conv_w, conv_b, xbc);
  dtcum<<<dim3(8, 128), 64, 0, stream>>>(proj, dt_bias, A_log, dtv, cumv, dlwv, cdec);
  ssd_intra<<<dim3(8, 128), 256, 0, stream>>>(xbc, dtv, cumv, dlwv, y, states);
  ssd_scan<<<4096, 256, 0, stream>>>(states, cdec, prev);
  ssd_inter<<<dim3(8, 128), 256, 0, stream>>>(xbc, cumv, prev, Dp, y);
  gate_norm<<<2048, 256, 0, stream>>>(y, proj, norm_w, g);
  gemm_bt<1><<<dim3(32, 16), 256, 0, stream>>>(g, out_w, out, 2048, HID_, INTER_);
}